// Round 24
// baseline (261.326 us; speedup 1.0000x reference)
//
#include <hip/hip_runtime.h>
#include <hip/hip_bf16.h>
#include <math.h>

typedef short short8 __attribute__((ext_vector_type(8)));
typedef float f32x16 __attribute__((ext_vector_type(16)));
typedef float f32x4v __attribute__((ext_vector_type(4)));
typedef float f32x2  __attribute__((ext_vector_type(2)));
typedef unsigned int u32;

#define B_ROWS 8192
#define IN_DIM 1024
#define OUT_DIM 256
#define M_DIM 1280
#define P_DIM 2304
#define NJ 10
#define RB 32                  // rows per block -> 256 blocks, 1 block/CU, 8 waves
#define BK 128
#define HG_COLS 1152

// ws: Xbf bf16[8192][1024] ; Wbf bf16[1280][2304] ; Hg bf16[8192][1152]
#define WBF_OFF (B_ROWS * (size_t)IN_DIM * 2)
#define HG_OFF  (WBF_OFF + (size_t)M_DIM * P_DIM * 2)

__device__ __forceinline__ short f2bf(float x)
{
    __hip_bfloat16 h = __float2bfloat16(x);
    return *(short*)&h;
}

// tanh = 1 - 2/(e^{2x}+1); saturates correctly at +-inf.
__device__ __forceinline__ float tanh_fast(float x)
{
    float e = __expf(2.f * x);
    return 1.f - 2.f * __builtin_amdgcn_rcpf(e + 1.f);
}

__device__ __forceinline__ float sigmoid_fast(float y)
{
    return __builtin_amdgcn_rcpf(1.f + __expf(-y));
}

// packed dual-f32 FMA: d += w * h (h broadcast from lo)
__device__ __forceinline__ void pk_fma_bcast(f32x2& d, f32x2 w, f32x2 h)
{
    asm("v_pk_fma_f32 %0, %1, %2, %0 op_sel_hi:[1,0,1]"
        : "+v"(d) : "v"(w), "v"(h));
}

// low-latency lane broadcast (VALU/SALU path, off the DS pipe)
__device__ __forceinline__ float rdlane(float v, int l)
{
    return __int_as_float(__builtin_amdgcn_readlane(__float_as_int(v), l));
}

// async global->LDS DMA, 16 B per lane
__device__ __forceinline__ void gld16(const void* g, void* l)
{
    __builtin_amdgcn_global_load_lds(
        (const __attribute__((address_space(1))) void*)g,
        (__attribute__((address_space(3))) void*)l, 16, 0, 0);
}

__global__ __launch_bounds__(256)
void convert_x(const float* __restrict__ x, short* __restrict__ Xbf)
{
    int idx = blockIdx.x * 256 + threadIdx.x;
    int r  = idx >> 7;
    int c8 = (idx & 127) << 3;
    const float* src = x + (size_t)r * IN_DIM + c8;
    float4 a0 = *(const float4*)src;
    float4 a1 = *(const float4*)(src + 4);
    short8 s;
    s[0] = f2bf(a0.x); s[1] = f2bf(a0.y); s[2] = f2bf(a0.z); s[3] = f2bf(a0.w);
    s[4] = f2bf(a1.x); s[5] = f2bf(a1.y); s[6] = f2bf(a1.z); s[7] = f2bf(a1.w);
    *(short8*)(Xbf + (size_t)r * IN_DIM + c8) = s;
}

__global__ __launch_bounds__(256)
void convert_w(const float* __restrict__ W, short* __restrict__ Wbf)
{
    size_t e8 = ((size_t)blockIdx.x * 256 + threadIdx.x) * 8;
    float4 a0 = *(const float4*)(W + e8);
    float4 a1 = *(const float4*)(W + e8 + 4);
    short8 s;
    s[0] = f2bf(a0.x); s[1] = f2bf(a0.y); s[2] = f2bf(a0.z); s[3] = f2bf(a0.w);
    s[4] = f2bf(a1.x); s[5] = f2bf(a1.y); s[6] = f2bf(a1.z); s[7] = f2bf(a1.w);
    *(short8*)(Wbf + e8) = s;
}

// LDS (84,480 B):
//  GEMM: buf0 {A @0 (8K), W @8192 (32K)} ; buf1 {A @40960, W @49152} (-> 81,920)
//  seq overlay (phase-disjoint): PreL f32[32][132] @0 (16,896) ;
//                                lwf f32[128][132] @16896 (67,584 -> 84,480)
#define XA0 0
#define XW0 8192
#define XA1 40960
#define XW1 49152
#define LWF_OFF 16896
#define PLS 132
#define LWSF 132   // f32 per lwf row (phys cols 0..131)

__global__ __launch_bounds__(512, 1)
void fused(const short* __restrict__ Xbf, const short* __restrict__ Wbf,
           const float* __restrict__ Wf, short* __restrict__ Hg,
           const float* __restrict__ bias, float* __restrict__ out)
{
    __shared__ __align__(16) char L[84480];

    const int tid  = threadIdx.x;
    const int lane = tid & 63;
    const int w    = tid >> 6;      // wave 0..7
    const int rl   = lane & 31;     // fragment row/col (32x32)
    const int lh   = lane >> 5;     // k-half within 16-chunk
    const int cg   = w >> 1;        // col group 0..3 (32 cols)
    const int kh   = w & 1;         // K-half 0/1
    const int r4   = lane & 3;      // seq: row within wave's 4
    const int sl   = lane >> 2;     // seq: slice 0..15 (8 u's)
    const int srow = w * 4 + r4;    // seq row 0..31
    const int bm   = blockIdx.x * RB;
    const int ccol = cg * 32 + rl;  // GEMM output col 0..127
    const int swz  = (rl & 15) << 4;
    // 2-way-free bank skew
    const int colb = sl * 8 + ((sl >> 3) << 2);   // f32 units, max 131

#pragma unroll 1
    for (int J = 0; J < NJ; ++J) {
        const int j0 = J * 128;
        const int nt = (IN_DIM + j0) / BK;   // 8 + J

        f32x16 acc;
#pragma unroll
        for (int r = 0; r < 16; ++r) acc[r] = 0.f;

        __syncthreads();   // prev J fully done

        // 5 DMA issues per wave per tile: 1 A-chunk (4 rows) + 4 W-chunks
        auto issue = [&](int k0, char* xb, char* wb) {
            {
                int R  = 4 * w + (lane >> 4);
                int sb = ((lane & 15) << 4) ^ ((R & 15) << 4);
                const short* g = (k0 < IN_DIM)
                    ? (Xbf + (size_t)(bm + R) * IN_DIM + k0)
                    : (Hg + (size_t)(bm + R) * HG_COLS + (k0 - IN_DIM));
                gld16((const char*)g + sb, xb + w * 1024);
            }
#pragma unroll
            for (int c = 0; c < 4; ++c) {
                int j  = 4 * w + c;              // W LDS row-quad 0..31
                int R  = 4 * j + (lane >> 4);    // W tile row 0..127
                int sb = ((lane & 15) << 4) ^ ((R & 15) << 4);
                const short* g = Wbf + (size_t)(j0 + R) * P_DIM + k0;
                gld16((const char*)g + sb, wb + j * 1024);
            }
        };
        auto domfma = [&](const char* xb, const char* wb) {
#pragma unroll
            for (int c = 0; c < 4; ++c) {
                int kb = kh * 128 + c * 32 + lh * 16;
                short8 a = *(const short8*)(xb + rl * 256 + (kb ^ swz));
                short8 b = *(const short8*)(wb + ccol * 256 + (kb ^ swz));
                acc = __builtin_amdgcn_mfma_f32_32x32x16_bf16(a, b, acc, 0, 0, 0);
            }
        };

        // ---- GEMM: DMA depth-2 pipeline, counted vmcnt ----
        issue(0, L + XA0, L + XW0);
        issue(BK, L + XA1, L + XW1);
#pragma unroll 1
        for (int t = 0; t < nt; ++t) {
            if (t + 1 < nt) asm volatile("s_waitcnt vmcnt(5)" ::: "memory");
            else            asm volatile("s_waitcnt vmcnt(0)" ::: "memory");
            __builtin_amdgcn_s_barrier();      // tile t fully in LDS
            const char* xb = (t & 1) ? L + XA1 : L + XA0;
            const char* wb = (t & 1) ? L + XW1 : L + XW0;
            domfma(xb, wb);
            asm volatile("s_waitcnt lgkmcnt(0)" ::: "memory");
            __builtin_amdgcn_s_barrier();      // all reads of buf[t&1] done
            if (t + 2 < nt)
                issue((t + 2) * BK, (t & 1) ? L + XA1 : L + XA0,
                                    (t & 1) ? L + XW1 : L + XW0);
        }

        // ---- epilogue: combine K-halves into PreL, then stage lwf f32 -----
        float* PreL = (float*)L;
        if (kh == 0) {
            float bv = bias[j0 + ccol];
#pragma unroll
            for (int r = 0; r < 16; ++r) {
                int rg = (r & 3) + 8 * (r >> 2) + 4 * lh;
                PreL[rg * PLS + ccol] = acc[r] + bv;
            }
        }
        __syncthreads();
        if (kh == 1) {
#pragma unroll
            for (int r = 0; r < 16; ++r) {
                int rg = (r & 3) + 8 * (r >> 2) + 4 * lh;
                PreL[rg * PLS + ccol] += acc[r];
            }
        }
        {
            float* lwf = (float*)(L + LWF_OFF);
            int u = tid & 127, th = tid >> 7;     // th 0..3
            int cu = u + ((u >> 6) << 2);         // skewed phys col, [0,131]
#pragma unroll
            for (int it = 0; it < 8; ++it) {
                int t4 = (it * 4 + th) * 4;
                float4 v = *(const float4*)(Wf + (size_t)(j0 + u) * P_DIM + IN_DIM + j0 + t4);
                lwf[(t4 + 0) * LWSF + cu] = (u > t4 + 0) ? v.x : 0.f;
                lwf[(t4 + 1) * LWSF + cu] = (u > t4 + 1) ? v.y : 0.f;
                lwf[(t4 + 2) * LWSF + cu] = (u > t4 + 2) ? v.z : 0.f;
                lwf[(t4 + 3) * LWSF + cu] = (u > t4 + 3) ? v.w : 0.f;
            }
        }
        __syncthreads();

        // ---- read PreL into seq register pairs (8 u's per lane) ----
        f32x2 a01, a23, a45, a67;
        {
            const float* pr = (const float*)L + srow * PLS + sl * 8;
            a01 = *(const f32x2*)pr;
            a23 = *(const f32x2*)(pr + 2);
            a45 = *(const f32x2*)(pr + 4);
            a67 = *(const f32x2*)(pr + 6);
        }

        // ---- 128 seq steps: ds_read(f32) + tanh + READLANE bcast + pk_fma -
        const float* lwb = (const float*)(L + LWF_OFF) + colb;
#pragma unroll 1
        for (int g = 0; g < 16; ++g) {
            const int  base = g << 2;
            const bool own  = (sl == g);
#pragma unroll
            for (int s = 0; s < 8; ++s) {
                const int t = g * 8 + s;
                f32x4v w0 = *(const f32x4v*)(lwb + t * LWSF);
                f32x4v w1 = *(const f32x4v*)(lwb + t * LWSF + 4);
                float ps;
                switch (s) {
                    case 0: ps = a01[0]; break; case 1: ps = a01[1]; break;
                    case 2: ps = a23[0]; break; case 3: ps = a23[1]; break;
                    case 4: ps = a45[0]; break; case 5: ps = a45[1]; break;
                    case 6: ps = a67[0]; break; default: ps = a67[1]; break;
                }
                float th_ = tanh_fast(ps);
                float b0 = rdlane(th_, base + 0);
                float b1 = rdlane(th_, base + 1);
                float b2 = rdlane(th_, base + 2);
                float b3 = rdlane(th_, base + 3);
                float h01 = (r4 & 1) ? b1 : b0;
                float h23 = (r4 & 1) ? b3 : b2;
                float h = (r4 & 2) ? h23 : h01;
                f32x2 hp; hp[0] = h; hp[1] = h;
                f32x2 q;
                q[0] = w0[0]; q[1] = w0[1]; pk_fma_bcast(a01, q, hp);
                q[0] = w0[2]; q[1] = w0[3]; pk_fma_bcast(a23, q, hp);
                q[0] = w1[0]; q[1] = w1[1]; pk_fma_bcast(a45, q, hp);
                q[0] = w1[2]; q[1] = w1[3]; pk_fma_bcast(a67, q, hp);
                if (own) {
                    switch (s) {
                        case 0: a01[0] = h; break; case 1: a01[1] = h; break;
                        case 2: a23[0] = h; break; case 3: a23[1] = h; break;
                        case 4: a45[0] = h; break; case 5: a45[1] = h; break;
                        case 6: a67[0] = h; break; default: a67[1] = h; break;
                    }
                }
            }
        }

        float as[8] = {a01[0], a01[1], a23[0], a23[1],
                       a45[0], a45[1], a67[0], a67[1]};

        // ---- write h to global H panel / output ----
        if (J < 9) {
            short8 hv;
#pragma unroll
            for (int e = 0; e < 8; ++e) hv[e] = f2bf(as[e]);
            *(short8*)(Hg + (size_t)(bm + srow) * HG_COLS + j0 + sl * 8) = hv;
        }
        if (J >= 8) {
            float* op = out + (size_t)(bm + srow) * OUT_DIM + (j0 - IN_DIM) + sl * 8;
            float4 o0, o1;
            o0.x = sigmoid_fast(as[0]); o0.y = sigmoid_fast(as[1]);
            o0.z = sigmoid_fast(as[2]); o0.w = sigmoid_fast(as[3]);
            o1.x = sigmoid_fast(as[4]); o1.y = sigmoid_fast(as[5]);
            o1.z = sigmoid_fast(as[6]); o1.w = sigmoid_fast(as[7]);
            *(float4*)op = o0;
            *(float4*)(op + 4) = o1;
        }
    }
}

extern "C" void kernel_launch(void* const* d_in, const int* in_sizes, int n_in,
                              void* d_out, int out_size, void* d_ws, size_t ws_size,
                              hipStream_t stream)
{
    const float* x    = (const float*)d_in[0];
    const float* W    = (const float*)d_in[1];
    const float* bias = (const float*)d_in[2];
    float* out = (float*)d_out;
    short* Xbf = (short*)d_ws;
    short* Wbf = (short*)((char*)d_ws + WBF_OFF);
    short* Hg  = (short*)((char*)d_ws + HG_OFF);

    convert_x<<<dim3(B_ROWS * IN_DIM / 8 / 256), dim3(256), 0, stream>>>(x, Xbf);
    convert_w<<<dim3(M_DIM * P_DIM / 8 / 256), dim3(256), 0, stream>>>(W, Wbf);
    fused<<<dim3(B_ROWS / RB), dim3(512), 0, stream>>>(Xbf, Wbf, W, Hg, bias, out);
}

// Round 25
// 238.994 us; speedup vs baseline: 1.0934x; 1.0934x over previous
//
#include <hip/hip_runtime.h>
#include <hip/hip_bf16.h>
#include <math.h>

typedef short short8 __attribute__((ext_vector_type(8)));
typedef float f32x16 __attribute__((ext_vector_type(16)));
typedef float f32x4v __attribute__((ext_vector_type(4)));
typedef float f32x2  __attribute__((ext_vector_type(2)));
typedef unsigned int u32;

#define B_ROWS 8192
#define IN_DIM 1024
#define OUT_DIM 256
#define M_DIM 1280
#define P_DIM 2304
#define NJ 10
#define RB 32                  // rows per block -> 256 blocks, 1 block/CU, 8 waves
#define BK 128
#define HG_COLS 1152

// ws: Xbf bf16[8192][1024] ; Wbf bf16[1280][2304] ; Hg bf16[8192][1152]
#define WBF_OFF (B_ROWS * (size_t)IN_DIM * 2)
#define HG_OFF  (WBF_OFF + (size_t)M_DIM * P_DIM * 2)

__device__ __forceinline__ short f2bf(float x)
{
    __hip_bfloat16 h = __float2bfloat16(x);
    return *(short*)&h;
}

// tanh = 1 - 2/(e^{2x}+1); saturates correctly at +-inf.
__device__ __forceinline__ float tanh_fast(float x)
{
    float e = __expf(2.f * x);
    return 1.f - 2.f * __builtin_amdgcn_rcpf(e + 1.f);
}

__device__ __forceinline__ float sigmoid_fast(float y)
{
    return __builtin_amdgcn_rcpf(1.f + __expf(-y));
}

// packed dual-f32 FMA: d += w * h (h broadcast from lo)
__device__ __forceinline__ void pk_fma_bcast(f32x2& d, f32x2 w, f32x2 h)
{
    asm("v_pk_fma_f32 %0, %1, %2, %0 op_sel_hi:[1,0,1]"
        : "+v"(d) : "v"(w), "v"(h));
}

// async global->LDS DMA, 16 B per lane
__device__ __forceinline__ void gld16(const void* g, void* l)
{
    __builtin_amdgcn_global_load_lds(
        (const __attribute__((address_space(1))) void*)g,
        (__attribute__((address_space(3))) void*)l, 16, 0, 0);
}

__global__ __launch_bounds__(256)
void convert_x(const float* __restrict__ x, short* __restrict__ Xbf)
{
    int idx = blockIdx.x * 256 + threadIdx.x;
    int r  = idx >> 7;
    int c8 = (idx & 127) << 3;
    const float* src = x + (size_t)r * IN_DIM + c8;
    float4 a0 = *(const float4*)src;
    float4 a1 = *(const float4*)(src + 4);
    short8 s;
    s[0] = f2bf(a0.x); s[1] = f2bf(a0.y); s[2] = f2bf(a0.z); s[3] = f2bf(a0.w);
    s[4] = f2bf(a1.x); s[5] = f2bf(a1.y); s[6] = f2bf(a1.z); s[7] = f2bf(a1.w);
    *(short8*)(Xbf + (size_t)r * IN_DIM + c8) = s;
}

__global__ __launch_bounds__(256)
void convert_w(const float* __restrict__ W, short* __restrict__ Wbf)
{
    size_t e8 = ((size_t)blockIdx.x * 256 + threadIdx.x) * 8;
    float4 a0 = *(const float4*)(W + e8);
    float4 a1 = *(const float4*)(W + e8 + 4);
    short8 s;
    s[0] = f2bf(a0.x); s[1] = f2bf(a0.y); s[2] = f2bf(a0.z); s[3] = f2bf(a0.w);
    s[4] = f2bf(a1.x); s[5] = f2bf(a1.y); s[6] = f2bf(a1.z); s[7] = f2bf(a1.w);
    *(short8*)(Wbf + e8) = s;
}

// LDS (84,480 B):
//  GEMM: buf0 {A @0 (8K), W @8192 (32K)} ; buf1 {A @40960, W @49152} (-> 81,920)
//  seq overlay (phase-disjoint): PreL f32[32][132] @0 (16,896) ;
//                                lwf f32[128][132] @16896 (67,584 -> 84,480)
#define XA0 0
#define XW0 8192
#define XA1 40960
#define XW1 49152
#define LWF_OFF 16896
#define PLS 132
#define LWSF 132   // f32 per lwf row (phys cols 0..131)

__global__ __launch_bounds__(512, 1)
void fused(const short* __restrict__ Xbf, const short* __restrict__ Wbf,
           const float* __restrict__ Wf, short* __restrict__ Hg,
           const float* __restrict__ bias, float* __restrict__ out)
{
    __shared__ __align__(16) char L[84480];

    const int tid  = threadIdx.x;
    const int lane = tid & 63;
    const int w    = tid >> 6;      // wave 0..7
    const int rl   = lane & 31;     // fragment row/col (32x32)
    const int lh   = lane >> 5;     // k-half within 16-chunk
    const int cg   = w >> 1;        // col group 0..3 (32 cols)
    const int kh   = w & 1;         // K-half 0/1
    const int r4   = lane & 3;      // seq: row within wave's 4
    const int sl   = lane >> 2;     // seq: slice 0..15 (8 u's)
    const int srow = w * 4 + r4;    // seq row 0..31
    const int bm   = blockIdx.x * RB;
    const int ccol = cg * 32 + rl;  // GEMM output col 0..127
    const int swz  = (rl & 15) << 4;
    // 2-way-free bank skew
    const int colb = sl * 8 + ((sl >> 3) << 2);   // f32 units, max 131

#pragma unroll 1
    for (int J = 0; J < NJ; ++J) {
        const int j0 = J * 128;
        const int nt = (IN_DIM + j0) / BK;   // 8 + J

        f32x16 acc;
#pragma unroll
        for (int r = 0; r < 16; ++r) acc[r] = 0.f;

        __syncthreads();   // prev J fully done

        // 5 DMA issues per wave per tile: 1 A-chunk (4 rows) + 4 W-chunks
        auto issue = [&](int k0, char* xb, char* wb) {
            {
                int R  = 4 * w + (lane >> 4);
                int sb = ((lane & 15) << 4) ^ ((R & 15) << 4);
                const short* g = (k0 < IN_DIM)
                    ? (Xbf + (size_t)(bm + R) * IN_DIM + k0)
                    : (Hg + (size_t)(bm + R) * HG_COLS + (k0 - IN_DIM));
                gld16((const char*)g + sb, xb + w * 1024);
            }
#pragma unroll
            for (int c = 0; c < 4; ++c) {
                int j  = 4 * w + c;              // W LDS row-quad 0..31
                int R  = 4 * j + (lane >> 4);    // W tile row 0..127
                int sb = ((lane & 15) << 4) ^ ((R & 15) << 4);
                const short* g = Wbf + (size_t)(j0 + R) * P_DIM + k0;
                gld16((const char*)g + sb, wb + j * 1024);
            }
        };
        auto domfma = [&](const char* xb, const char* wb) {
#pragma unroll
            for (int c = 0; c < 4; ++c) {
                int kb = kh * 128 + c * 32 + lh * 16;
                short8 a = *(const short8*)(xb + rl * 256 + (kb ^ swz));
                short8 b = *(const short8*)(wb + ccol * 256 + (kb ^ swz));
                acc = __builtin_amdgcn_mfma_f32_32x32x16_bf16(a, b, acc, 0, 0, 0);
            }
        };

        // ---- GEMM: DMA depth-2 pipeline, counted vmcnt ----
        issue(0, L + XA0, L + XW0);
        issue(BK, L + XA1, L + XW1);
#pragma unroll 1
        for (int t = 0; t < nt; ++t) {
            if (t + 1 < nt) asm volatile("s_waitcnt vmcnt(5)" ::: "memory");
            else            asm volatile("s_waitcnt vmcnt(0)" ::: "memory");
            __builtin_amdgcn_s_barrier();      // tile t fully in LDS
            const char* xb = (t & 1) ? L + XA1 : L + XA0;
            const char* wb = (t & 1) ? L + XW1 : L + XW0;
            domfma(xb, wb);
            asm volatile("s_waitcnt lgkmcnt(0)" ::: "memory");
            __builtin_amdgcn_s_barrier();      // all reads of buf[t&1] done
            if (t + 2 < nt)
                issue((t + 2) * BK, (t & 1) ? L + XA1 : L + XA0,
                                    (t & 1) ? L + XW1 : L + XW0);
        }

        // ---- epilogue: combine K-halves into PreL, then stage lwf f32 -----
        float* PreL = (float*)L;
        if (kh == 0) {
            float bv = bias[j0 + ccol];
#pragma unroll
            for (int r = 0; r < 16; ++r) {
                int rg = (r & 3) + 8 * (r >> 2) + 4 * lh;
                PreL[rg * PLS + ccol] = acc[r] + bv;
            }
        }
        __syncthreads();
        if (kh == 1) {
#pragma unroll
            for (int r = 0; r < 16; ++r) {
                int rg = (r & 3) + 8 * (r >> 2) + 4 * lh;
                PreL[rg * PLS + ccol] += acc[r];
            }
        }
        {
            float* lwf = (float*)(L + LWF_OFF);
            int u = tid & 127, th = tid >> 7;     // th 0..3
            int cu = u + ((u >> 6) << 2);         // skewed phys col, [0,131]
#pragma unroll
            for (int it = 0; it < 8; ++it) {
                int t4 = (it * 4 + th) * 4;
                float4 v = *(const float4*)(Wf + (size_t)(j0 + u) * P_DIM + IN_DIM + j0 + t4);
                lwf[(t4 + 0) * LWSF + cu] = (u > t4 + 0) ? v.x : 0.f;
                lwf[(t4 + 1) * LWSF + cu] = (u > t4 + 1) ? v.y : 0.f;
                lwf[(t4 + 2) * LWSF + cu] = (u > t4 + 2) ? v.z : 0.f;
                lwf[(t4 + 3) * LWSF + cu] = (u > t4 + 3) ? v.w : 0.f;
            }
        }
        __syncthreads();

        // ---- read PreL into seq register pairs (8 u's per lane) ----
        f32x2 a01, a23, a45, a67;
        {
            const float* pr = (const float*)L + srow * PLS + sl * 8;
            a01 = *(const f32x2*)pr;
            a23 = *(const f32x2*)(pr + 2);
            a45 = *(const f32x2*)(pr + 4);
            a67 = *(const f32x2*)(pr + 6);
        }

        // ---- seq: 16 groups of 8; micro-triangle + shfl burst -------------
        // Owner slice (sl==g) holds exactly the intra-group weights, so its
        // 8-step triangle runs broadcast-free; one 8-shfl burst per group.
        const float* lwb = (const float*)(L + LWF_OFF) + colb;
#pragma unroll 1
        for (int g = 0; g < 16; ++g) {
            const int  hsrc = r4 | (g << 2);
            const bool own  = (sl == g);

            // burst-load this group's 16 weight quads (one LDS latency)
            f32x4v wq[16];
#pragma unroll
            for (int s = 0; s < 8; ++s) {
                wq[2 * s]     = *(const f32x4v*)(lwb + (g * 8 + s) * LWSF);
                wq[2 * s + 1] = *(const f32x4v*)(lwb + (g * 8 + s) * LWSF + 4);
            }

            // micro-triangle on private regs (meaningful on owner lanes only)
            float tt[8], hh[8];
            tt[0] = a01[0]; tt[1] = a01[1]; tt[2] = a23[0]; tt[3] = a23[1];
            tt[4] = a45[0]; tt[5] = a45[1]; tt[6] = a67[0]; tt[7] = a67[1];
#pragma unroll
            for (int s = 0; s < 8; ++s) {
                hh[s] = tanh_fast(tt[s]);
#pragma unroll
                for (int e = s + 1; e < 8; ++e) {
                    float wv = (e < 4) ? wq[2 * s][e] : wq[2 * s + 1][e - 4];
                    tt[e] += wv * hh[s];
                }
            }

            // broadcast the owner's 8 h values (one burst)
            float hb[8];
#pragma unroll
            for (int s = 0; s < 8; ++s) hb[s] = __shfl(hh[s], hsrc);

            // rank-8 update via pk_fma (tri-zeros make past terms no-ops)
#pragma unroll
            for (int s = 0; s < 8; ++s) {
                f32x2 hp; hp[0] = hb[s]; hp[1] = hb[s];
                f32x2 q;
                q[0] = wq[2 * s][0]; q[1] = wq[2 * s][1];
                pk_fma_bcast(a01, q, hp);
                q[0] = wq[2 * s][2]; q[1] = wq[2 * s][3];
                pk_fma_bcast(a23, q, hp);
                q[0] = wq[2 * s + 1][0]; q[1] = wq[2 * s + 1][1];
                pk_fma_bcast(a45, q, hp);
                q[0] = wq[2 * s + 1][2]; q[1] = wq[2 * s + 1][3];
                pk_fma_bcast(a67, q, hp);
            }
            if (own) {
                a01[0] = hb[0]; a01[1] = hb[1]; a23[0] = hb[2]; a23[1] = hb[3];
                a45[0] = hb[4]; a45[1] = hb[5]; a67[0] = hb[6]; a67[1] = hb[7];
            }
        }

        float as[8] = {a01[0], a01[1], a23[0], a23[1],
                       a45[0], a45[1], a67[0], a67[1]};

        // ---- write h to global H panel / output ----
        if (J < 9) {
            short8 hv;
#pragma unroll
            for (int e = 0; e < 8; ++e) hv[e] = f2bf(as[e]);
            *(short8*)(Hg + (size_t)(bm + srow) * HG_COLS + j0 + sl * 8) = hv;
        }
        if (J >= 8) {
            float* op = out + (size_t)(bm + srow) * OUT_DIM + (j0 - IN_DIM) + sl * 8;
            float4 o0, o1;
            o0.x = sigmoid_fast(as[0]); o0.y = sigmoid_fast(as[1]);
            o0.z = sigmoid_fast(as[2]); o0.w = sigmoid_fast(as[3]);
            o1.x = sigmoid_fast(as[4]); o1.y = sigmoid_fast(as[5]);
            o1.z = sigmoid_fast(as[6]); o1.w = sigmoid_fast(as[7]);
            *(float4*)op = o0;
            *(float4*)(op + 4) = o1;
        }
    }
}

extern "C" void kernel_launch(void* const* d_in, const int* in_sizes, int n_in,
                              void* d_out, int out_size, void* d_ws, size_t ws_size,
                              hipStream_t stream)
{
    const float* x    = (const float*)d_in[0];
    const float* W    = (const float*)d_in[1];
    const float* bias = (const float*)d_in[2];
    float* out = (float*)d_out;
    short* Xbf = (short*)d_ws;
    short* Wbf = (short*)((char*)d_ws + WBF_OFF);
    short* Hg  = (short*)((char*)d_ws + HG_OFF);

    convert_x<<<dim3(B_ROWS * IN_DIM / 8 / 256), dim3(256), 0, stream>>>(x, Xbf);
    convert_w<<<dim3(M_DIM * P_DIM / 8 / 256), dim3(256), 0, stream>>>(W, Wbf);
    fused<<<dim3(B_ROWS / RB), dim3(512), 0, stream>>>(Xbf, Wbf, W, Hg, bias, out);
}

// Round 26
// 223.646 us; speedup vs baseline: 1.1685x; 1.0686x over previous
//
#include <hip/hip_runtime.h>
#include <hip/hip_bf16.h>
#include <math.h>

typedef short short8 __attribute__((ext_vector_type(8)));
typedef float f32x16 __attribute__((ext_vector_type(16)));
typedef float f32x4v __attribute__((ext_vector_type(4)));
typedef float f32x2  __attribute__((ext_vector_type(2)));
typedef unsigned int u32;

#define B_ROWS 8192
#define IN_DIM 1024
#define OUT_DIM 256
#define M_DIM 1280
#define P_DIM 2304
#define NJ 10
#define RB 32                  // rows per block -> 256 blocks, 1 block/CU, 8 waves
#define BK 128
#define HG_COLS 1152

// ws: Xbf bf16[8192][1024] ; Wbf bf16[1280][2304] ; Hg bf16[8192][1152]
#define WBF_OFF (B_ROWS * (size_t)IN_DIM * 2)
#define HG_OFF  (WBF_OFF + (size_t)M_DIM * P_DIM * 2)

__device__ __forceinline__ short f2bf(float x)
{
    __hip_bfloat16 h = __float2bfloat16(x);
    return *(short*)&h;
}

// tanh = 1 - 2/(e^{2x}+1); saturates correctly at +-inf.
__device__ __forceinline__ float tanh_fast(float x)
{
    float e = __expf(2.f * x);
    return 1.f - 2.f * __builtin_amdgcn_rcpf(e + 1.f);
}

__device__ __forceinline__ float sigmoid_fast(float y)
{
    return __builtin_amdgcn_rcpf(1.f + __expf(-y));
}

// packed dual-f32 FMA: d += w * h (h broadcast from lo)
__device__ __forceinline__ void pk_fma_bcast(f32x2& d, f32x2 w, f32x2 h)
{
    asm("v_pk_fma_f32 %0, %1, %2, %0 op_sel_hi:[1,0,1]"
        : "+v"(d) : "v"(w), "v"(h));
}

// async global->LDS DMA, 16 B per lane
__device__ __forceinline__ void gld16(const void* g, void* l)
{
    __builtin_amdgcn_global_load_lds(
        (const __attribute__((address_space(1))) void*)g,
        (__attribute__((address_space(3))) void*)l, 16, 0, 0);
}

__global__ __launch_bounds__(256)
void convert_x(const float* __restrict__ x, short* __restrict__ Xbf)
{
    int idx = blockIdx.x * 256 + threadIdx.x;
    int r  = idx >> 7;
    int c8 = (idx & 127) << 3;
    const float* src = x + (size_t)r * IN_DIM + c8;
    float4 a0 = *(const float4*)src;
    float4 a1 = *(const float4*)(src + 4);
    short8 s;
    s[0] = f2bf(a0.x); s[1] = f2bf(a0.y); s[2] = f2bf(a0.z); s[3] = f2bf(a0.w);
    s[4] = f2bf(a1.x); s[5] = f2bf(a1.y); s[6] = f2bf(a1.z); s[7] = f2bf(a1.w);
    *(short8*)(Xbf + (size_t)r * IN_DIM + c8) = s;
}

__global__ __launch_bounds__(256)
void convert_w(const float* __restrict__ W, short* __restrict__ Wbf)
{
    size_t e8 = ((size_t)blockIdx.x * 256 + threadIdx.x) * 8;
    float4 a0 = *(const float4*)(W + e8);
    float4 a1 = *(const float4*)(W + e8 + 4);
    short8 s;
    s[0] = f2bf(a0.x); s[1] = f2bf(a0.y); s[2] = f2bf(a0.z); s[3] = f2bf(a0.w);
    s[4] = f2bf(a1.x); s[5] = f2bf(a1.y); s[6] = f2bf(a1.z); s[7] = f2bf(a1.w);
    *(short8*)(Wbf + e8) = s;
}

// LDS (84,480 B):
//  GEMM: buf0 {A @0 (8K), W @8192 (32K)} ; buf1 {A @40960, W @49152} (-> 81,920)
//  seq overlay (phase-disjoint): PreL f32[32][132] @0 (16,896) ;
//                                lwf f32[128][132] @16896 (67,584 -> 84,480)
#define XA0 0
#define XW0 8192
#define XA1 40960
#define XW1 49152
#define LWF_OFF 16896
#define PLS 132
#define LWSF 132   // f32 per lwf row (phys cols 0..131)

__global__ __launch_bounds__(512, 1)
void fused(const short* __restrict__ Xbf, const short* __restrict__ Wbf,
           const float* __restrict__ Wf, short* __restrict__ Hg,
           const float* __restrict__ bias, float* __restrict__ out)
{
    __shared__ __align__(16) char L[84480];

    const int tid  = threadIdx.x;
    const int lane = tid & 63;
    const int w    = tid >> 6;      // wave 0..7
    const int rl   = lane & 31;     // fragment row/col (32x32)
    const int lh   = lane >> 5;     // k-half within 16-chunk
    const int cg   = w >> 1;        // col group 0..3 (32 cols)
    const int kh   = w & 1;         // K-half 0/1
    const int r4   = lane & 3;      // seq: row within wave's 4
    const int sl   = lane >> 2;     // seq: slice 0..15 (8 u's)
    const int srow = w * 4 + r4;    // seq row 0..31
    const int bm   = blockIdx.x * RB;
    const int ccol = cg * 32 + rl;  // GEMM output col 0..127
    const int swz  = (rl & 15) << 4;
    // 2-way-free bank skew
    const int colb = sl * 8 + ((sl >> 3) << 2);   // f32 units, max 131

#pragma unroll 1
    for (int J = 0; J < NJ; ++J) {
        const int j0 = J * 128;
        const int nt = (IN_DIM + j0) / BK;   // 8 + J

        f32x16 acc;
#pragma unroll
        for (int r = 0; r < 16; ++r) acc[r] = 0.f;

        __syncthreads();   // prev J fully done

        // 5 DMA issues per wave per tile: 1 A-chunk (4 rows) + 4 W-chunks
        auto issue = [&](int k0, char* xb, char* wb) {
            {
                int R  = 4 * w + (lane >> 4);
                int sb = ((lane & 15) << 4) ^ ((R & 15) << 4);
                const short* g = (k0 < IN_DIM)
                    ? (Xbf + (size_t)(bm + R) * IN_DIM + k0)
                    : (Hg + (size_t)(bm + R) * HG_COLS + (k0 - IN_DIM));
                gld16((const char*)g + sb, xb + w * 1024);
            }
#pragma unroll
            for (int c = 0; c < 4; ++c) {
                int j  = 4 * w + c;              // W LDS row-quad 0..31
                int R  = 4 * j + (lane >> 4);    // W tile row 0..127
                int sb = ((lane & 15) << 4) ^ ((R & 15) << 4);
                const short* g = Wbf + (size_t)(j0 + R) * P_DIM + k0;
                gld16((const char*)g + sb, wb + j * 1024);
            }
        };
        auto domfma = [&](const char* xb, const char* wb) {
#pragma unroll
            for (int c = 0; c < 4; ++c) {
                int kb = kh * 128 + c * 32 + lh * 16;
                short8 a = *(const short8*)(xb + rl * 256 + (kb ^ swz));
                short8 b = *(const short8*)(wb + ccol * 256 + (kb ^ swz));
                acc = __builtin_amdgcn_mfma_f32_32x32x16_bf16(a, b, acc, 0, 0, 0);
            }
        };

        // ---- GEMM: DMA depth-2 pipeline, counted vmcnt ----
        issue(0, L + XA0, L + XW0);
        issue(BK, L + XA1, L + XW1);
#pragma unroll 1
        for (int t = 0; t < nt; ++t) {
            if (t + 1 < nt) asm volatile("s_waitcnt vmcnt(5)" ::: "memory");
            else            asm volatile("s_waitcnt vmcnt(0)" ::: "memory");
            __builtin_amdgcn_s_barrier();      // tile t fully in LDS
            const char* xb = (t & 1) ? L + XA1 : L + XA0;
            const char* wb = (t & 1) ? L + XW1 : L + XW0;
            domfma(xb, wb);
            asm volatile("s_waitcnt lgkmcnt(0)" ::: "memory");
            __builtin_amdgcn_s_barrier();      // all reads of buf[t&1] done
            if (t + 2 < nt)
                issue((t + 2) * BK, (t & 1) ? L + XA1 : L + XA0,
                                    (t & 1) ? L + XW1 : L + XW0);
        }

        // ---- epilogue: combine K-halves into PreL, then stage lwf f32 -----
        float* PreL = (float*)L;
        if (kh == 0) {
            float bv = bias[j0 + ccol];
#pragma unroll
            for (int r = 0; r < 16; ++r) {
                int rg = (r & 3) + 8 * (r >> 2) + 4 * lh;
                PreL[rg * PLS + ccol] = acc[r] + bv;
            }
        }
        __syncthreads();
        if (kh == 1) {
#pragma unroll
            for (int r = 0; r < 16; ++r) {
                int rg = (r & 3) + 8 * (r >> 2) + 4 * lh;
                PreL[rg * PLS + ccol] += acc[r];
            }
        }
        {
            float* lwf = (float*)(L + LWF_OFF);
            int u = tid & 127, th = tid >> 7;     // th 0..3
            int cu = u + ((u >> 6) << 2);         // skewed phys col, [0,131]
#pragma unroll
            for (int it = 0; it < 8; ++it) {
                int t4 = (it * 4 + th) * 4;
                float4 v = *(const float4*)(Wf + (size_t)(j0 + u) * P_DIM + IN_DIM + j0 + t4);
                lwf[(t4 + 0) * LWSF + cu] = (u > t4 + 0) ? v.x : 0.f;
                lwf[(t4 + 1) * LWSF + cu] = (u > t4 + 1) ? v.y : 0.f;
                lwf[(t4 + 2) * LWSF + cu] = (u > t4 + 2) ? v.z : 0.f;
                lwf[(t4 + 3) * LWSF + cu] = (u > t4 + 3) ? v.w : 0.f;
            }
        }
        __syncthreads();

        // ---- read PreL into seq register pairs (8 u's per lane) ----
        f32x2 a01, a23, a45, a67;
        {
            const float* pr = (const float*)L + srow * PLS + sl * 8;
            a01 = *(const f32x2*)pr;
            a23 = *(const f32x2*)(pr + 2);
            a45 = *(const f32x2*)(pr + 4);
            a67 = *(const f32x2*)(pr + 6);
        }

        // ---- 128 seq steps: 2 ds_read_b128(f32) + shfl + 4 pk_fma ---------
        const float* lwb = (const float*)(L + LWF_OFF) + colb;
#pragma unroll 1
        for (int g = 0; g < 16; ++g) {
            const int  hsrc = r4 | (g << 2);
            const bool own  = (sl == g);
#pragma unroll
            for (int s = 0; s < 8; ++s) {
                const int t = g * 8 + s;
                f32x4v w0 = *(const f32x4v*)(lwb + t * LWSF);
                f32x4v w1 = *(const f32x4v*)(lwb + t * LWSF + 4);
                float ps;
                switch (s) {
                    case 0: ps = a01[0]; break; case 1: ps = a01[1]; break;
                    case 2: ps = a23[0]; break; case 3: ps = a23[1]; break;
                    case 4: ps = a45[0]; break; case 5: ps = a45[1]; break;
                    case 6: ps = a67[0]; break; default: ps = a67[1]; break;
                }
                float th_ = tanh_fast(ps);
                float h = __shfl(th_, hsrc);
                f32x2 hp; hp[0] = h; hp[1] = h;
                f32x2 q;
                q[0] = w0[0]; q[1] = w0[1]; pk_fma_bcast(a01, q, hp);
                q[0] = w0[2]; q[1] = w0[3]; pk_fma_bcast(a23, q, hp);
                q[0] = w1[0]; q[1] = w1[1]; pk_fma_bcast(a45, q, hp);
                q[0] = w1[2]; q[1] = w1[3]; pk_fma_bcast(a67, q, hp);
                if (own) {
                    switch (s) {
                        case 0: a01[0] = h; break; case 1: a01[1] = h; break;
                        case 2: a23[0] = h; break; case 3: a23[1] = h; break;
                        case 4: a45[0] = h; break; case 5: a45[1] = h; break;
                        case 6: a67[0] = h; break; default: a67[1] = h; break;
                    }
                }
            }
        }

        float as[8] = {a01[0], a01[1], a23[0], a23[1],
                       a45[0], a45[1], a67[0], a67[1]};

        // ---- write h to global H panel / output ----
        if (J < 9) {
            short8 hv;
#pragma unroll
            for (int e = 0; e < 8; ++e) hv[e] = f2bf(as[e]);
            *(short8*)(Hg + (size_t)(bm + srow) * HG_COLS + j0 + sl * 8) = hv;
        }
        if (J >= 8) {
            float* op = out + (size_t)(bm + srow) * OUT_DIM + (j0 - IN_DIM) + sl * 8;
            float4 o0, o1;
            o0.x = sigmoid_fast(as[0]); o0.y = sigmoid_fast(as[1]);
            o0.z = sigmoid_fast(as[2]); o0.w = sigmoid_fast(as[3]);
            o1.x = sigmoid_fast(as[4]); o1.y = sigmoid_fast(as[5]);
            o1.z = sigmoid_fast(as[6]); o1.w = sigmoid_fast(as[7]);
            *(float4*)op = o0;
            *(float4*)(op + 4) = o1;
        }
    }
}

extern "C" void kernel_launch(void* const* d_in, const int* in_sizes, int n_in,
                              void* d_out, int out_size, void* d_ws, size_t ws_size,
                              hipStream_t stream)
{
    const float* x    = (const float*)d_in[0];
    const float* W    = (const float*)d_in[1];
    const float* bias = (const float*)d_in[2];
    float* out = (float*)d_out;
    short* Xbf = (short*)d_ws;
    short* Wbf = (short*)((char*)d_ws + WBF_OFF);
    short* Hg  = (short*)((char*)d_ws + HG_OFF);

    convert_x<<<dim3(B_ROWS * IN_DIM / 8 / 256), dim3(256), 0, stream>>>(x, Xbf);
    convert_w<<<dim3(M_DIM * P_DIM / 8 / 256), dim3(256), 0, stream>>>(W, Wbf);
    fused<<<dim3(B_ROWS / RB), dim3(512), 0, stream>>>(Xbf, Wbf, W, Hg, bias, out);
}

// Round 27
// 221.916 us; speedup vs baseline: 1.1776x; 1.0078x over previous
//
#include <hip/hip_runtime.h>
#include <hip/hip_bf16.h>
#include <math.h>

typedef short short8 __attribute__((ext_vector_type(8)));
typedef float f32x16 __attribute__((ext_vector_type(16)));
typedef float f32x4v __attribute__((ext_vector_type(4)));
typedef float f32x2  __attribute__((ext_vector_type(2)));
typedef unsigned int u32;

#define B_ROWS 8192
#define IN_DIM 1024
#define OUT_DIM 256
#define M_DIM 1280
#define P_DIM 2304
#define NJ 10
#define RB 32                  // rows per block -> 256 blocks, 1 block/CU, 8 waves
#define BK 128
#define HG_COLS 1152

// ws: Xbf bf16[8192][1024] ; Wbf bf16[1280][2304] ; Hg bf16[8192][1152]
#define WBF_OFF (B_ROWS * (size_t)IN_DIM * 2)
#define HG_OFF  (WBF_OFF + (size_t)M_DIM * P_DIM * 2)

__device__ __forceinline__ short f2bf(float x)
{
    __hip_bfloat16 h = __float2bfloat16(x);
    return *(short*)&h;
}

// tanh = 1 - 2/(e^{2x}+1); saturates correctly at +-inf.
__device__ __forceinline__ float tanh_fast(float x)
{
    float e = __expf(2.f * x);
    return 1.f - 2.f * __builtin_amdgcn_rcpf(e + 1.f);
}

__device__ __forceinline__ float sigmoid_fast(float y)
{
    return __builtin_amdgcn_rcpf(1.f + __expf(-y));
}

// packed dual-f32 FMA: d += w * h (h broadcast from lo)
__device__ __forceinline__ void pk_fma_bcast(f32x2& d, f32x2 w, f32x2 h)
{
    asm("v_pk_fma_f32 %0, %1, %2, %0 op_sel_hi:[1,0,1]"
        : "+v"(d) : "v"(w), "v"(h));
}

// async global->LDS DMA, 16 B per lane
__device__ __forceinline__ void gld16(const void* g, void* l)
{
    __builtin_amdgcn_global_load_lds(
        (const __attribute__((address_space(1))) void*)g,
        (__attribute__((address_space(3))) void*)l, 16, 0, 0);
}

__global__ __launch_bounds__(256)
void convert_x(const float* __restrict__ x, short* __restrict__ Xbf)
{
    int idx = blockIdx.x * 256 + threadIdx.x;
    int r  = idx >> 7;
    int c8 = (idx & 127) << 3;
    const float* src = x + (size_t)r * IN_DIM + c8;
    float4 a0 = *(const float4*)src;
    float4 a1 = *(const float4*)(src + 4);
    short8 s;
    s[0] = f2bf(a0.x); s[1] = f2bf(a0.y); s[2] = f2bf(a0.z); s[3] = f2bf(a0.w);
    s[4] = f2bf(a1.x); s[5] = f2bf(a1.y); s[6] = f2bf(a1.z); s[7] = f2bf(a1.w);
    *(short8*)(Xbf + (size_t)r * IN_DIM + c8) = s;
}

__global__ __launch_bounds__(256)
void convert_w(const float* __restrict__ W, short* __restrict__ Wbf)
{
    size_t e8 = ((size_t)blockIdx.x * 256 + threadIdx.x) * 8;
    float4 a0 = *(const float4*)(W + e8);
    float4 a1 = *(const float4*)(W + e8 + 4);
    short8 s;
    s[0] = f2bf(a0.x); s[1] = f2bf(a0.y); s[2] = f2bf(a0.z); s[3] = f2bf(a0.w);
    s[4] = f2bf(a1.x); s[5] = f2bf(a1.y); s[6] = f2bf(a1.z); s[7] = f2bf(a1.w);
    *(short8*)(Wbf + e8) = s;
}

// LDS (122,880 B), triple-buffered GEMM staging:
//  buf0 {A @0, W @8192} ; buf1 {A @40960, W @49152} ; buf2 {A @81920, W @90112}
//  seq overlay (phase-disjoint): PreL f32[32][132] @0 (16,896) ;
//                                lwf f32[128][132] @16896 (67,584 -> 84,480)
#define XA0 0
#define XW0 8192
#define XA1 40960
#define XW1 49152
#define XA2 81920
#define XW2 90112
#define LWF_OFF 16896
#define PLS 132
#define LWSF 132   // f32 per lwf row (phys cols 0..131)

__global__ __launch_bounds__(512, 1)
void fused(const short* __restrict__ Xbf, const short* __restrict__ Wbf,
           const float* __restrict__ Wf, short* __restrict__ Hg,
           const float* __restrict__ bias, float* __restrict__ out)
{
    __shared__ __align__(16) char L[122880];

    const int tid  = threadIdx.x;
    const int lane = tid & 63;
    const int w    = tid >> 6;      // wave 0..7
    const int rl   = lane & 31;     // fragment row/col (32x32)
    const int lh   = lane >> 5;     // k-half within 16-chunk
    const int cg   = w >> 1;        // col group 0..3 (32 cols)
    const int kh   = w & 1;         // K-half 0/1
    const int r4   = lane & 3;      // seq: row within wave's 4
    const int sl   = lane >> 2;     // seq: slice 0..15 (8 u's)
    const int srow = w * 4 + r4;    // seq row 0..31
    const int bm   = blockIdx.x * RB;
    const int ccol = cg * 32 + rl;  // GEMM output col 0..127
    const int swz  = (rl & 15) << 4;
    // 2-way-free bank skew
    const int colb = sl * 8 + ((sl >> 3) << 2);   // f32 units, max 131

#pragma unroll 1
    for (int J = 0; J < NJ; ++J) {
        const int j0 = J * 128;
        const int nt = (IN_DIM + j0) / BK;   // 8 + J

        f32x16 acc;
#pragma unroll
        for (int r = 0; r < 16; ++r) acc[r] = 0.f;

        __syncthreads();   // prev J fully done (seq reads of overlay finished)

        // 5 DMA issues per wave per tile: 1 A-chunk (4 rows) + 4 W-chunks
        auto issue = [&](int k0, char* xb, char* wb) {
            {
                int R  = 4 * w + (lane >> 4);
                int sb = ((lane & 15) << 4) ^ ((R & 15) << 4);
                const short* g = (k0 < IN_DIM)
                    ? (Xbf + (size_t)(bm + R) * IN_DIM + k0)
                    : (Hg + (size_t)(bm + R) * HG_COLS + (k0 - IN_DIM));
                gld16((const char*)g + sb, xb + w * 1024);
            }
#pragma unroll
            for (int c = 0; c < 4; ++c) {
                int j  = 4 * w + c;              // W LDS row-quad 0..31
                int R  = 4 * j + (lane >> 4);    // W tile row 0..127
                int sb = ((lane & 15) << 4) ^ ((R & 15) << 4);
                const short* g = Wbf + (size_t)(j0 + R) * P_DIM + k0;
                gld16((const char*)g + sb, wb + j * 1024);
            }
        };
        auto domfma = [&](const char* xb, const char* wb) {
#pragma unroll
            for (int c = 0; c < 4; ++c) {
                int kb = kh * 128 + c * 32 + lh * 16;
                short8 a = *(const short8*)(xb + rl * 256 + (kb ^ swz));
                short8 b = *(const short8*)(wb + ccol * 256 + (kb ^ swz));
                acc = __builtin_amdgcn_mfma_f32_32x32x16_bf16(a, b, acc, 0, 0, 0);
            }
        };

        // ---- GEMM: DMA depth-3 pipeline, counted vmcnt --------------------
        char *xbA = L + XA0, *wbA = L + XW0;   // tile t
        char *xbB = L + XA1, *wbB = L + XW1;   // tile t+1
        char *xbC = L + XA2, *wbC = L + XW2;   // tile t+2
        issue(0, xbA, wbA);
        issue(BK, xbB, wbB);
        issue(2 * BK, xbC, wbC);
#pragma unroll 1
        for (int t = 0; t < nt; ++t) {
            if (t + 2 < nt)      asm volatile("s_waitcnt vmcnt(10)" ::: "memory");
            else if (t + 1 < nt) asm volatile("s_waitcnt vmcnt(5)" ::: "memory");
            else                 asm volatile("s_waitcnt vmcnt(0)" ::: "memory");
            __builtin_amdgcn_s_barrier();      // tile t fully in LDS
            domfma(xbA, wbA);
            asm volatile("s_waitcnt lgkmcnt(0)" ::: "memory");
            __builtin_amdgcn_s_barrier();      // all reads of tile-t buf done
            if (t + 3 < nt) issue((t + 3) * BK, xbA, wbA);
            char* tx = xbA; xbA = xbB; xbB = xbC; xbC = tx;
            char* tw = wbA; wbA = wbB; wbB = wbC; wbC = tw;
        }

        // ---- epilogue: combine K-halves into PreL, then stage lwf f32 -----
        float* PreL = (float*)L;
        if (kh == 0) {
            float bv = bias[j0 + ccol];
#pragma unroll
            for (int r = 0; r < 16; ++r) {
                int rg = (r & 3) + 8 * (r >> 2) + 4 * lh;
                PreL[rg * PLS + ccol] = acc[r] + bv;
            }
        }
        __syncthreads();
        if (kh == 1) {
#pragma unroll
            for (int r = 0; r < 16; ++r) {
                int rg = (r & 3) + 8 * (r >> 2) + 4 * lh;
                PreL[rg * PLS + ccol] += acc[r];
            }
        }
        {
            float* lwf = (float*)(L + LWF_OFF);
            int u = tid & 127, th = tid >> 7;     // th 0..3
            int cu = u + ((u >> 6) << 2);         // skewed phys col, [0,131]
#pragma unroll
            for (int it = 0; it < 8; ++it) {
                int t4 = (it * 4 + th) * 4;
                float4 v = *(const float4*)(Wf + (size_t)(j0 + u) * P_DIM + IN_DIM + j0 + t4);
                lwf[(t4 + 0) * LWSF + cu] = (u > t4 + 0) ? v.x : 0.f;
                lwf[(t4 + 1) * LWSF + cu] = (u > t4 + 1) ? v.y : 0.f;
                lwf[(t4 + 2) * LWSF + cu] = (u > t4 + 2) ? v.z : 0.f;
                lwf[(t4 + 3) * LWSF + cu] = (u > t4 + 3) ? v.w : 0.f;
            }
        }
        __syncthreads();

        // ---- read PreL into seq register pairs (8 u's per lane) ----
        f32x2 a01, a23, a45, a67;
        {
            const float* pr = (const float*)L + srow * PLS + sl * 8;
            a01 = *(const f32x2*)pr;
            a23 = *(const f32x2*)(pr + 2);
            a45 = *(const f32x2*)(pr + 4);
            a67 = *(const f32x2*)(pr + 6);
        }

        // ---- 128 seq steps: 2 ds_read_b128(f32) + shfl + 4 pk_fma ---------
        const float* lwb = (const float*)(L + LWF_OFF) + colb;
#pragma unroll 1
        for (int g = 0; g < 16; ++g) {
            const int  hsrc = r4 | (g << 2);
            const bool own  = (sl == g);
#pragma unroll
            for (int s = 0; s < 8; ++s) {
                const int t = g * 8 + s;
                f32x4v w0 = *(const f32x4v*)(lwb + t * LWSF);
                f32x4v w1 = *(const f32x4v*)(lwb + t * LWSF + 4);
                float ps;
                switch (s) {
                    case 0: ps = a01[0]; break; case 1: ps = a01[1]; break;
                    case 2: ps = a23[0]; break; case 3: ps = a23[1]; break;
                    case 4: ps = a45[0]; break; case 5: ps = a45[1]; break;
                    case 6: ps = a67[0]; break; default: ps = a67[1]; break;
                }
                float th_ = tanh_fast(ps);
                float h = __shfl(th_, hsrc);
                f32x2 hp; hp[0] = h; hp[1] = h;
                f32x2 q;
                q[0] = w0[0]; q[1] = w0[1]; pk_fma_bcast(a01, q, hp);
                q[0] = w0[2]; q[1] = w0[3]; pk_fma_bcast(a23, q, hp);
                q[0] = w1[0]; q[1] = w1[1]; pk_fma_bcast(a45, q, hp);
                q[0] = w1[2]; q[1] = w1[3]; pk_fma_bcast(a67, q, hp);
                if (own) {
                    switch (s) {
                        case 0: a01[0] = h; break; case 1: a01[1] = h; break;
                        case 2: a23[0] = h; break; case 3: a23[1] = h; break;
                        case 4: a45[0] = h; break; case 5: a45[1] = h; break;
                        case 6: a67[0] = h; break; default: a67[1] = h; break;
                    }
                }
            }
        }

        float as[8] = {a01[0], a01[1], a23[0], a23[1],
                       a45[0], a45[1], a67[0], a67[1]};

        // ---- write h to global H panel / output ----
        if (J < 9) {
            short8 hv;
#pragma unroll
            for (int e = 0; e < 8; ++e) hv[e] = f2bf(as[e]);
            *(short8*)(Hg + (size_t)(bm + srow) * HG_COLS + j0 + sl * 8) = hv;
        }
        if (J >= 8) {
            float* op = out + (size_t)(bm + srow) * OUT_DIM + (j0 - IN_DIM) + sl * 8;
            float4 o0, o1;
            o0.x = sigmoid_fast(as[0]); o0.y = sigmoid_fast(as[1]);
            o0.z = sigmoid_fast(as[2]); o0.w = sigmoid_fast(as[3]);
            o1.x = sigmoid_fast(as[4]); o1.y = sigmoid_fast(as[5]);
            o1.z = sigmoid_fast(as[6]); o1.w = sigmoid_fast(as[7]);
            *(float4*)op = o0;
            *(float4*)(op + 4) = o1;
        }
    }
}

extern "C" void kernel_launch(void* const* d_in, const int* in_sizes, int n_in,
                              void* d_out, int out_size, void* d_ws, size_t ws_size,
                              hipStream_t stream)
{
    const float* x    = (const float*)d_in[0];
    const float* W    = (const float*)d_in[1];
    const float* bias = (const float*)d_in[2];
    float* out = (float*)d_out;
    short* Xbf = (short*)d_ws;
    short* Wbf = (short*)((char*)d_ws + WBF_OFF);
    short* Hg  = (short*)((char*)d_ws + HG_OFF);

    convert_x<<<dim3(B_ROWS * IN_DIM / 8 / 256), dim3(256), 0, stream>>>(x, Xbf);
    convert_w<<<dim3(M_DIM * P_DIM / 8 / 256), dim3(256), 0, stream>>>(W, Wbf);
    fused<<<dim3(B_ROWS / RB), dim3(512), 0, stream>>>(Xbf, Wbf, W, Hg, bias, out);
}